// Round 4
// baseline (291.210 us; speedup 1.0000x reference)
//
#include <hip/hip_runtime.h>

typedef _Float16 half8 __attribute__((ext_vector_type(8)));
typedef _Float16 half4v __attribute__((ext_vector_type(4)));
typedef float   float4v __attribute__((ext_vector_type(4)));

#define S_LEN 4096
#define NBATCH 4
#define NCHUNK 8          // K-split factor: each chunk covers S/NCHUNK keys
// ws layout in halves:
//   cnt  @ 0        : 128 ints (split-K done counters)  [reuses old w16 area]
//   Qh   @ 32768    : 16384*64     = 1048576   (token-major [B*S][64])
//   Kh   @ 1081344  : 16384*64     = 1048576
//   Vt   @ 2129920  : 4*128*4096   = 2097152   (per-batch [128][S], PERMUTED per
//                     64-key tile: key k=grp*32+g*16+q*4+r stored at grp*32+q*8+g*4+r)
//   L    @ 4227072  : 16384 floats (row sum-of-exp accumulators)
#define WS_QH  32768
#define WS_KH  1081344
#define WS_VT  2129920
#define WS_L   4227072

static __device__ __forceinline__ half8 cvt8(float4v f0, float4v f1) {
    half8 h;
    h[0] = (_Float16)f0[0]; h[1] = (_Float16)f0[1];
    h[2] = (_Float16)f0[2]; h[3] = (_Float16)f0[3];
    h[4] = (_Float16)f1[0]; h[5] = (_Float16)f1[1];
    h[6] = (_Float16)f1[2]; h[7] = (_Float16)f1[3];
    return h;
}

// ---------------- kernel 1: QKV projection (fused init) -----------------------
// grid 1024 blocks x 256 thr; block owns 16 tokens; wave w owns oc [w*64, +64):
//   wave 0 -> Q, wave 1 -> K, waves 2,3 -> V.
// No LDS: x and W fragments are read directly from global (L1/L2-hot; W is
// converted fp32->fp16 in-register). Each block also zeroes its slice of
// out/lbuf and block 0 zeroes the split-K counters (all complete before flash).
__global__ __launch_bounds__(256) void qkv_proj_kernel(const float* __restrict__ x,
                                                       const float* __restrict__ Wq,
                                                       const float* __restrict__ Wk,
                                                       const float* __restrict__ Wv,
                                                       _Float16* __restrict__ Qh,
                                                       _Float16* __restrict__ Kh,
                                                       _Float16* __restrict__ Vt,
                                                       float4v* __restrict__ out4,
                                                       float4v* __restrict__ l4,
                                                       int* __restrict__ cnt) {
    const int t = threadIdx.x, blk = blockIdx.x;

    // ---- zeroing duty (out: 524288 float4 / 1024 blocks = 512/block) ----
    {
        float4v z = (float4v){0.f, 0.f, 0.f, 0.f};
        out4[blk * 512 + t]       = z;
        out4[blk * 512 + 256 + t] = z;
        if (t < 4) l4[blk * 4 + t] = z;          // lbuf: 4096 float4
        if (blk == 0 && t < 128) cnt[t] = 0;
    }

    const int w = t >> 6, lane = t & 63, quad = lane >> 4, n16 = lane & 15;
    const float* xb = x + (size_t)blk * 16 * 128;

    // A fragments: token n16, d = c*32 + quad*8 .. +8  (direct global, L1-shared)
    half8 a[4];
#pragma unroll
    for (int c = 0; c < 4; ++c) {
        const float* xr = xb + n16 * 128 + c * 32 + quad * 8;
        a[c] = cvt8(*(const float4v*)xr, *(const float4v*)(xr + 4));
    }

    const float* Wsel = (w == 0) ? Wq : (w == 1) ? Wk : Wv;
    const int rowoff = (w >= 2) ? (w - 2) * 64 : 0;

    float4v acc[4];
#pragma unroll
    for (int nb = 0; nb < 4; ++nb) acc[nb] = (float4v){0.f, 0.f, 0.f, 0.f};

#pragma unroll
    for (int c = 0; c < 4; ++c)
#pragma unroll
        for (int nb = 0; nb < 4; ++nb) {
            const float* wr = Wsel + (size_t)(rowoff + nb * 16 + n16) * 128 + c * 32 + quad * 8;
            half8 bfr = cvt8(*(const float4v*)wr, *(const float4v*)(wr + 4));
            acc[nb] = __builtin_amdgcn_mfma_f32_16x16x32_f16(a[c], bfr, acc[nb], 0, 0, 0);
        }

    const int token0 = blk * 16 + quad * 4;
    if (w == 0) {
        for (int nb = 0; nb < 4; ++nb)
            for (int r = 0; r < 4; ++r)
                Qh[(size_t)(token0 + r) * 64 + nb * 16 + n16] = (_Float16)acc[nb][r];
    } else if (w == 1) {
        for (int nb = 0; nb < 4; ++nb)
            for (int r = 0; r < 4; ++r)
                Kh[(size_t)(token0 + r) * 64 + nb * 16 + n16] = (_Float16)acc[nb][r];
    } else {
        // V store, PERMUTED within each 64-key tile so flash reads b128 frags:
        // key s -> pos = kt*64 + grp*32 + q*8 + g*4 + r  (s = kt*64+grp*32+g*16+q*4+r)
        const int bb = token0 >> 12, s0 = token0 & 4095;
        const int kt = s0 >> 6, k0 = s0 & 63;
        const int grp = k0 >> 5, k32 = k0 & 31;
        const int g = k32 >> 4, q = (k32 >> 2) & 3;
        const int off = kt * 64 + grp * 32 + q * 8 + g * 4;       // r spans 0..3
        for (int nb = 0; nb < 4; ++nb) {
            const int vc = (w - 2) * 64 + nb * 16 + n16;
            half4v h;
            h[0] = (_Float16)acc[nb][0]; h[1] = (_Float16)acc[nb][1];
            h[2] = (_Float16)acc[nb][2]; h[3] = (_Float16)acc[nb][3];
            *(half4v*)&Vt[((size_t)bb * 128 + vc) * S_LEN + off] = h;
        }
    }
}

// ---------------- kernel 2: flash attention, no-LDS, K-split x8 ---------------
// grid (S/128, NCHUNK, B), 256 threads. Wave w owns q rows:
//   set A: qt*128 + w*16 + [0,16)      set B: qt*128 + 64 + w*16 + [0,16)
// NO LDS, NO barriers in the loop: K/V fragments load directly from global.
// Per-CU working set (K 8KB + V 16KB per tile) is L1-resident; waves run free.
// SWAPPED QK^T (mfma(K,Q)) keeps q lane-local -> P stays in registers; PV uses
// the permuted-K order baked into Vt's layout (see qkv), so V frags are b128.
// Shifted-exp softmax: p = exp(s*0.125 - 4) -- exactly additive across chunks;
// accumulate via HW fp32 atomics; last-arriving chunk normalizes (split-K fixup).
#define KT 64
__global__ __launch_bounds__(256) void flash_kernel(const _Float16* __restrict__ Qh,
                                                    const _Float16* __restrict__ Kh,
                                                    const _Float16* __restrict__ Vt,
                                                    float* __restrict__ out,
                                                    float* __restrict__ lbuf,
                                                    int* __restrict__ cnt) {
    __shared__ int sflag;

    const int t = threadIdx.x;
    const int qt = blockIdx.x, chunk = blockIdx.y, b = blockIdx.z;
    const int w = t >> 6, lane = t & 63, quad = lane >> 4, n16 = lane & 15;

    const size_t qrowA = (size_t)b * S_LEN + qt * 128 + w * 16 + n16;
    const size_t qrowB = qrowA + 64;
    half8 aQ0A = *(const half8*)&Qh[qrowA * 64 + quad * 8];
    half8 aQ1A = *(const half8*)&Qh[qrowA * 64 + 32 + quad * 8];
    half8 aQ0B = *(const half8*)&Qh[qrowB * 64 + quad * 8];
    half8 aQ1B = *(const half8*)&Qh[qrowB * 64 + 32 + quad * 8];

    float4v OA[8], OB[8];
#pragma unroll
    for (int vb = 0; vb < 8; ++vb) {
        OA[vb] = (float4v){0.f, 0.f, 0.f, 0.f};
        OB[vb] = (float4v){0.f, 0.f, 0.f, 0.f};
    }
    float lsumA = 0.f, lsumB = 0.f;

    const _Float16* Kb = Kh + (size_t)b * S_LEN * 64;
    const _Float16* Vb = Vt + (size_t)b * 128 * S_LEN;

    const int kt0 = chunk * (S_LEN / KT / NCHUNK);
    const int kt1 = kt0 + (S_LEN / KT / NCHUNK);

    for (int kt = kt0; kt < kt1; ++kt) {
        const _Float16* Ktile = Kb + (size_t)kt * KT * 64;

        // -------- QK^T (swapped) + softmax; P packed into A-fragments --------
        half8 aP0A, aP1A, aP0B, aP1B;
        __builtin_amdgcn_s_setprio(1);
#pragma unroll
        for (int nb = 0; nb < 4; ++nb) {
            half8 bK0 = *(const half8*)&Ktile[(nb * 16 + n16) * 64 + quad * 8];
            half8 bK1 = *(const half8*)&Ktile[(nb * 16 + n16) * 64 + 32 + quad * 8];
            float4v scA = (float4v){0.f, 0.f, 0.f, 0.f};
            float4v scB = (float4v){0.f, 0.f, 0.f, 0.f};
            scA = __builtin_amdgcn_mfma_f32_16x16x32_f16(bK0, aQ0A, scA, 0, 0, 0);
            scA = __builtin_amdgcn_mfma_f32_16x16x32_f16(bK1, aQ1A, scA, 0, 0, 0);
            scB = __builtin_amdgcn_mfma_f32_16x16x32_f16(bK0, aQ0B, scB, 0, 0, 0);
            scB = __builtin_amdgcn_mfma_f32_16x16x32_f16(bK1, aQ1B, scB, 0, 0, 0);
#pragma unroll
            for (int r = 0; r < 4; ++r) {
                // exp(s*0.125 - 4) == exp2(fma(s, 0.125*log2e, -4*log2e))
                float pa = __builtin_amdgcn_exp2f(__builtin_fmaf(scA[r], 0.18033688f, -5.7707802f));
                lsumA += pa;
                float pb = __builtin_amdgcn_exp2f(__builtin_fmaf(scB[r], 0.18033688f, -5.7707802f));
                lsumB += pb;
                int slot = (nb & 1) * 4 + r;
                if (nb < 2) { aP0A[slot] = (_Float16)pa; aP0B[slot] = (_Float16)pb; }
                else        { aP1A[slot] = (_Float16)pa; aP1B[slot] = (_Float16)pb; }
            }
        }
        __builtin_amdgcn_s_setprio(0);

        // -------- PV: V frags are contiguous b128 thanks to permuted layout ---
        __builtin_amdgcn_s_setprio(1);
#pragma unroll
        for (int vb = 0; vb < 8; ++vb) {
            const _Float16* vrow = &Vb[(size_t)(vb * 16 + n16) * S_LEN + kt * 64];
            half8 bV0 = *(const half8*)&vrow[quad * 8];
            half8 bV1 = *(const half8*)&vrow[32 + quad * 8];
            OA[vb] = __builtin_amdgcn_mfma_f32_16x16x32_f16(aP0A, bV0, OA[vb], 0, 0, 0);
            OA[vb] = __builtin_amdgcn_mfma_f32_16x16x32_f16(aP1A, bV1, OA[vb], 0, 0, 0);
            OB[vb] = __builtin_amdgcn_mfma_f32_16x16x32_f16(aP0B, bV0, OB[vb], 0, 0, 0);
            OB[vb] = __builtin_amdgcn_mfma_f32_16x16x32_f16(aP1B, bV1, OB[vb], 0, 0, 0);
        }
        __builtin_amdgcn_s_setprio(0);
    }

    // each lane holds the partial row-sum for q = n16; reduce across quads
    lsumA += __shfl_xor(lsumA, 16);
    lsumA += __shfl_xor(lsumA, 32);
    lsumB += __shfl_xor(lsumB, 16);
    lsumB += __shfl_xor(lsumB, 32);

    const int rowbaseA = qt * 128 + w * 16;                 // within batch
    const int rowbaseB = rowbaseA + 64;
    if (quad == 0) {
        unsafeAtomicAdd(&lbuf[b * S_LEN + rowbaseA + n16], lsumA);
        unsafeAtomicAdd(&lbuf[b * S_LEN + rowbaseB + n16], lsumB);
    }

    const int row0A = rowbaseA + quad * 4;
    const int row0B = rowbaseB + quad * 4;
    float* obA = out + ((size_t)b * S_LEN + row0A) * 128;
    float* obB = out + ((size_t)b * S_LEN + row0B) * 128;
#pragma unroll
    for (int vb = 0; vb < 8; ++vb)
#pragma unroll
        for (int r = 0; r < 4; ++r) {
            unsafeAtomicAdd(&obA[(size_t)r * 128 + vb * 16 + n16], OA[vb][r]);
            unsafeAtomicAdd(&obB[(size_t)r * 128 + vb * 16 + n16], OB[vb][r]);
        }

    // -------- split-K fixup: last-arriving chunk normalizes this row-group ----
    __threadfence();                 // make this block's atomics agent-visible
    __syncthreads();                 // all threads fenced
    if (t == 0) {
        int old = atomicAdd(&cnt[b * 32 + qt], 1);
        sflag = (old == NCHUNK - 1);
    }
    __syncthreads();
    if (sflag) {
        __threadfence();             // acquire: see other chunks' atomics
        float* ob = out + ((size_t)b * S_LEN + qt * 128) * 128;
        const float* lb = lbuf + b * S_LEN + qt * 128;
        for (int i = t; i < 128 * 128; i += 256) {
            int row = i >> 7;
            float l = __hip_atomic_load(&lb[row], __ATOMIC_RELAXED, __HIP_MEMORY_SCOPE_AGENT);
            float v = __hip_atomic_load(&ob[i], __ATOMIC_RELAXED, __HIP_MEMORY_SCOPE_AGENT);
            ob[i] = v * (1.0f / l);
        }
    }
}

// ---------------- launch ------------------------------------------------------
extern "C" void kernel_launch(void* const* d_in, const int* in_sizes, int n_in,
                              void* d_out, int out_size, void* d_ws, size_t ws_size,
                              hipStream_t stream) {
    const float* x  = (const float*)d_in[0];
    const float* Wq = (const float*)d_in[1];
    const float* Wk = (const float*)d_in[2];
    const float* Wv = (const float*)d_in[3];
    float* out = (float*)d_out;

    _Float16* ws = (_Float16*)d_ws;
    int*      cnt  = (int*)d_ws;
    _Float16* Qh   = ws + WS_QH;
    _Float16* Kh   = ws + WS_KH;
    _Float16* Vt   = ws + WS_VT;
    float*    lbuf = (float*)(ws + WS_L);

    qkv_proj_kernel<<<NBATCH * S_LEN / 16, 256, 0, stream>>>(x, Wq, Wk, Wv, Qh, Kh, Vt,
                                                             (float4v*)out, (float4v*)lbuf, cnt);
    flash_kernel<<<dim3(S_LEN / 128, NCHUNK, NBATCH), 256, 0, stream>>>(Qh, Kh, Vt, out, lbuf, cnt);
}

// Round 5
// 183.505 us; speedup vs baseline: 1.5869x; 1.5869x over previous
//
#include <hip/hip_runtime.h>

typedef _Float16 half8 __attribute__((ext_vector_type(8)));
typedef _Float16 half4v __attribute__((ext_vector_type(4)));
typedef float   float4v __attribute__((ext_vector_type(4)));

#define S_LEN 4096
#define NBATCH 4
#define NCHUNK 4          // K-split factor: each chunk covers S/NCHUNK keys
// ws layout in halves:
//   cnt  @ 0        : 128 ints (split-K done counters)
//   Qh   @ 32768    : 16384*64     = 1048576   (token-major [B*S][64])
//   Kh   @ 1081344  : 16384*64     = 1048576
//   Vt   @ 2129920  : 4*128*4096   = 2097152   (per-batch [128][S], PERMUTED per
//                     64-key tile: key k=grp*32+g*16+q*4+r stored at grp*32+q*8+g*4+r)
//   L    @ 4227072  : 16384 floats (row sum-of-exp accumulators)
#define WS_QH  32768
#define WS_KH  1081344
#define WS_VT  2129920
#define WS_L   4227072

static __device__ __forceinline__ half8 cvt8(float4v f0, float4v f1) {
    half8 h;
    h[0] = (_Float16)f0[0]; h[1] = (_Float16)f0[1];
    h[2] = (_Float16)f0[2]; h[3] = (_Float16)f0[3];
    h[4] = (_Float16)f1[0]; h[5] = (_Float16)f1[1];
    h[6] = (_Float16)f1[2]; h[7] = (_Float16)f1[3];
    return h;
}

// ---------------- kernel 1: QKV projection (fused init) -----------------------
// grid 1024 blocks x 256 thr; block owns 16 tokens; wave w owns oc [w*64, +64):
//   wave 0 -> Q, wave 1 -> K, waves 2,3 -> V.
// No LDS: x and W fragments are read directly from global (L1/L2-hot; W is
// converted fp32->fp16 in-register). Each block also zeroes its slice of
// out/lbuf and block 0 zeroes the split-K counters (all complete before flash).
__global__ __launch_bounds__(256) void qkv_proj_kernel(const float* __restrict__ x,
                                                       const float* __restrict__ Wq,
                                                       const float* __restrict__ Wk,
                                                       const float* __restrict__ Wv,
                                                       _Float16* __restrict__ Qh,
                                                       _Float16* __restrict__ Kh,
                                                       _Float16* __restrict__ Vt,
                                                       float4v* __restrict__ out4,
                                                       float4v* __restrict__ l4,
                                                       int* __restrict__ cnt) {
    const int t = threadIdx.x, blk = blockIdx.x;

    // ---- zeroing duty (out: 524288 float4 / 1024 blocks = 512/block) ----
    {
        float4v z = (float4v){0.f, 0.f, 0.f, 0.f};
        out4[blk * 512 + t]       = z;
        out4[blk * 512 + 256 + t] = z;
        if (t < 4) l4[blk * 4 + t] = z;          // lbuf: 4096 float4
        if (blk == 0 && t < 128) cnt[t] = 0;
    }

    const int w = t >> 6, lane = t & 63, quad = lane >> 4, n16 = lane & 15;
    const float* xb = x + (size_t)blk * 16 * 128;

    // A fragments: token n16, d = c*32 + quad*8 .. +8  (direct global, L1-shared)
    half8 a[4];
#pragma unroll
    for (int c = 0; c < 4; ++c) {
        const float* xr = xb + n16 * 128 + c * 32 + quad * 8;
        a[c] = cvt8(*(const float4v*)xr, *(const float4v*)(xr + 4));
    }

    const float* Wsel = (w == 0) ? Wq : (w == 1) ? Wk : Wv;
    const int rowoff = (w >= 2) ? (w - 2) * 64 : 0;

    float4v acc[4];
#pragma unroll
    for (int nb = 0; nb < 4; ++nb) acc[nb] = (float4v){0.f, 0.f, 0.f, 0.f};

#pragma unroll
    for (int c = 0; c < 4; ++c)
#pragma unroll
        for (int nb = 0; nb < 4; ++nb) {
            const float* wr = Wsel + (size_t)(rowoff + nb * 16 + n16) * 128 + c * 32 + quad * 8;
            half8 bfr = cvt8(*(const float4v*)wr, *(const float4v*)(wr + 4));
            acc[nb] = __builtin_amdgcn_mfma_f32_16x16x32_f16(a[c], bfr, acc[nb], 0, 0, 0);
        }

    const int token0 = blk * 16 + quad * 4;
    if (w == 0) {
        for (int nb = 0; nb < 4; ++nb)
            for (int r = 0; r < 4; ++r)
                Qh[(size_t)(token0 + r) * 64 + nb * 16 + n16] = (_Float16)acc[nb][r];
    } else if (w == 1) {
        for (int nb = 0; nb < 4; ++nb)
            for (int r = 0; r < 4; ++r)
                Kh[(size_t)(token0 + r) * 64 + nb * 16 + n16] = (_Float16)acc[nb][r];
    } else {
        // V store, PERMUTED within each 64-key tile so flash reads b128 frags:
        // key s -> pos = kt*64 + grp*32 + q*8 + g*4 + r  (s = kt*64+grp*32+g*16+q*4+r)
        const int bb = token0 >> 12, s0 = token0 & 4095;
        const int kt = s0 >> 6, k0 = s0 & 63;
        const int grp = k0 >> 5, k32 = k0 & 31;
        const int g = k32 >> 4, q = (k32 >> 2) & 3;
        const int off = kt * 64 + grp * 32 + q * 8 + g * 4;       // r spans 0..3
        for (int nb = 0; nb < 4; ++nb) {
            const int vc = (w - 2) * 64 + nb * 16 + n16;
            half4v h;
            h[0] = (_Float16)acc[nb][0]; h[1] = (_Float16)acc[nb][1];
            h[2] = (_Float16)acc[nb][2]; h[3] = (_Float16)acc[nb][3];
            *(half4v*)&Vt[((size_t)bb * 128 + vc) * S_LEN + off] = h;
        }
    }
}

// ---------------- kernel 2: flash attention, K-split x4, dbuf LDS -------------
// grid (S/128, NCHUNK, B), 256 threads. Wave w owns q rows:
//   set A: qt*128 + w*16 + [0,16)      set B: qt*128 + 64 + w*16 + [0,16)
// Double-buffered LDS, ONE barrier per iteration: compute[cur] -> write
// prefetched regs into buf[cur^1] -> barrier. Waves may drift one iteration
// apart, overlapping one wave's softmax (VALU/trans) with another's MFMA.
// SWAPPED QK^T (mfma(K,Q)) keeps q lane-local -> P stays in registers; the
// permuted Vt layout makes PV's V fragments contiguous b128 in LDS.
// Shifted-exp softmax: p = exp(s*0.125 - 4) -- exactly additive across chunks;
// accumulate via HW fp32 atomics; last-arriving chunk normalizes (split-K fixup).
#define KT 64
__global__ __launch_bounds__(256) void flash_kernel(const _Float16* __restrict__ Qh,
                                                    const _Float16* __restrict__ Kh,
                                                    const _Float16* __restrict__ Vt,
                                                    float* __restrict__ out,
                                                    float* __restrict__ lbuf,
                                                    int* __restrict__ cnt) {
    __shared__ _Float16 Ks[2][KT * 72];       // K tile [64][64], padded stride 72
    __shared__ _Float16 Vs[2][128 * 72];      // V^T tile [128][64] (permuted cols)
    __shared__ int sflag;

    const int t = threadIdx.x;
    const int qt = blockIdx.x, chunk = blockIdx.y, b = blockIdx.z;
    const int w = t >> 6, lane = t & 63, quad = lane >> 4, n16 = lane & 15;

    const size_t qrowA = (size_t)b * S_LEN + qt * 128 + w * 16 + n16;
    const size_t qrowB = qrowA + 64;
    half8 aQ0A = *(const half8*)&Qh[qrowA * 64 + quad * 8];
    half8 aQ1A = *(const half8*)&Qh[qrowA * 64 + 32 + quad * 8];
    half8 aQ0B = *(const half8*)&Qh[qrowB * 64 + quad * 8];
    half8 aQ1B = *(const half8*)&Qh[qrowB * 64 + 32 + quad * 8];

    float4v OA[8], OB[8];
#pragma unroll
    for (int vb = 0; vb < 8; ++vb) {
        OA[vb] = (float4v){0.f, 0.f, 0.f, 0.f};
        OB[vb] = (float4v){0.f, 0.f, 0.f, 0.f};
    }
    float lsumA = 0.f, lsumB = 0.f;

    const _Float16* Kb = Kh + (size_t)b * S_LEN * 64;
    const _Float16* Vb = Vt + (size_t)b * 128 * S_LEN;

    const int kt0 = chunk * (S_LEN / KT / NCHUNK);
    const int kt1 = kt0 + (S_LEN / KT / NCHUNK);

    const int kr0 = t >> 3, kc0 = t & 7;
    const int kr1 = (t + 256) >> 3;

    // -------- prologue: tile kt0 -> regs -> buf0; issue loads for kt0+1 -------
    half8 kreg0, kreg1, vreg[4];
    {
        const half8* srcK = (const half8*)(Kb + (size_t)kt0 * KT * 64);
        kreg0 = srcK[t];
        kreg1 = srcK[t + 256];
#pragma unroll
        for (int it = 0; it < 4; ++it) {
            int i = t + it * 256, row = i >> 3, c8 = i & 7;
            vreg[it] = *(const half8*)&Vb[(size_t)row * S_LEN + kt0 * KT + c8 * 8];
        }
    }
    *(half8*)&Ks[0][kr0 * 72 + kc0 * 8] = kreg0;
    *(half8*)&Ks[0][kr1 * 72 + kc0 * 8] = kreg1;
#pragma unroll
    for (int it = 0; it < 4; ++it) {
        int i = t + it * 256, row = i >> 3, c8 = i & 7;
        *(half8*)&Vs[0][row * 72 + c8 * 8] = vreg[it];
    }
    if (kt0 + 1 < kt1) {
        const half8* srcK = (const half8*)(Kb + (size_t)(kt0 + 1) * KT * 64);
        kreg0 = srcK[t];
        kreg1 = srcK[t + 256];
#pragma unroll
        for (int it = 0; it < 4; ++it) {
            int i = t + it * 256, row = i >> 3, c8 = i & 7;
            vreg[it] = *(const half8*)&Vb[(size_t)row * S_LEN + (kt0 + 1) * KT + c8 * 8];
        }
    }
    __syncthreads();

    int cur = 0;
    for (int kt = kt0; kt < kt1; ++kt) {
        const _Float16* Kcur = Ks[cur];
        const _Float16* Vcur = Vs[cur];

        // -------- QK^T (swapped) + softmax; P packed into A-fragments --------
        half8 aP0A, aP1A, aP0B, aP1B;
        __builtin_amdgcn_s_setprio(1);
#pragma unroll
        for (int nb = 0; nb < 4; ++nb) {
            half8 bK0 = *(const half8*)&Kcur[(nb * 16 + n16) * 72 + quad * 8];
            half8 bK1 = *(const half8*)&Kcur[(nb * 16 + n16) * 72 + 32 + quad * 8];
            float4v scA = (float4v){0.f, 0.f, 0.f, 0.f};
            float4v scB = (float4v){0.f, 0.f, 0.f, 0.f};
            scA = __builtin_amdgcn_mfma_f32_16x16x32_f16(bK0, aQ0A, scA, 0, 0, 0);
            scA = __builtin_amdgcn_mfma_f32_16x16x32_f16(bK1, aQ1A, scA, 0, 0, 0);
            scB = __builtin_amdgcn_mfma_f32_16x16x32_f16(bK0, aQ0B, scB, 0, 0, 0);
            scB = __builtin_amdgcn_mfma_f32_16x16x32_f16(bK1, aQ1B, scB, 0, 0, 0);
#pragma unroll
            for (int r = 0; r < 4; ++r) {
                // exp(s*0.125 - 4) == exp2(fma(s, 0.125*log2e, -4*log2e))
                float pa = __builtin_amdgcn_exp2f(__builtin_fmaf(scA[r], 0.18033688f, -5.7707802f));
                lsumA += pa;
                float pb = __builtin_amdgcn_exp2f(__builtin_fmaf(scB[r], 0.18033688f, -5.7707802f));
                lsumB += pb;
                int slot = (nb & 1) * 4 + r;
                if (nb < 2) { aP0A[slot] = (_Float16)pa; aP0B[slot] = (_Float16)pb; }
                else        { aP1A[slot] = (_Float16)pa; aP1B[slot] = (_Float16)pb; }
            }
        }
        __builtin_amdgcn_s_setprio(0);

        // -------- PV: V frags contiguous b128 thanks to permuted layout -------
        __builtin_amdgcn_s_setprio(1);
#pragma unroll
        for (int vb = 0; vb < 8; ++vb) {
            const _Float16* vrow = &Vcur[(vb * 16 + n16) * 72];
            half8 bV0 = *(const half8*)&vrow[quad * 8];
            half8 bV1 = *(const half8*)&vrow[32 + quad * 8];
            OA[vb] = __builtin_amdgcn_mfma_f32_16x16x32_f16(aP0A, bV0, OA[vb], 0, 0, 0);
            OA[vb] = __builtin_amdgcn_mfma_f32_16x16x32_f16(aP1A, bV1, OA[vb], 0, 0, 0);
            OB[vb] = __builtin_amdgcn_mfma_f32_16x16x32_f16(aP0B, bV0, OB[vb], 0, 0, 0);
            OB[vb] = __builtin_amdgcn_mfma_f32_16x16x32_f16(aP1B, bV1, OB[vb], 0, 0, 0);
        }
        __builtin_amdgcn_s_setprio(0);

        // -------- stage tile kt+1 (already in regs) into buf[cur^1] ----------
        if (kt + 1 < kt1) {
            int nxt = cur ^ 1;
            *(half8*)&Ks[nxt][kr0 * 72 + kc0 * 8] = kreg0;
            *(half8*)&Ks[nxt][kr1 * 72 + kc0 * 8] = kreg1;
#pragma unroll
            for (int it = 0; it < 4; ++it) {
                int i = t + it * 256, row = i >> 3, c8 = i & 7;
                *(half8*)&Vs[nxt][row * 72 + c8 * 8] = vreg[it];
            }
            if (kt + 2 < kt1) {
                const half8* srcK = (const half8*)(Kb + (size_t)(kt + 2) * KT * 64);
                kreg0 = srcK[t];
                kreg1 = srcK[t + 256];
#pragma unroll
                for (int it = 0; it < 4; ++it) {
                    int i = t + it * 256, row = i >> 3, c8 = i & 7;
                    vreg[it] = *(const half8*)&Vb[(size_t)row * S_LEN + (kt + 2) * KT + c8 * 8];
                }
            }
            __syncthreads();
            cur = nxt;
        }
    }

    // each lane holds the partial row-sum for q = n16; reduce across quads
    lsumA += __shfl_xor(lsumA, 16);
    lsumA += __shfl_xor(lsumA, 32);
    lsumB += __shfl_xor(lsumB, 16);
    lsumB += __shfl_xor(lsumB, 32);

    const int rowbaseA = qt * 128 + w * 16;                 // within batch
    const int rowbaseB = rowbaseA + 64;
    if (quad == 0) {
        unsafeAtomicAdd(&lbuf[b * S_LEN + rowbaseA + n16], lsumA);
        unsafeAtomicAdd(&lbuf[b * S_LEN + rowbaseB + n16], lsumB);
    }

    const int row0A = rowbaseA + quad * 4;
    const int row0B = rowbaseB + quad * 4;
    float* obA = out + ((size_t)b * S_LEN + row0A) * 128;
    float* obB = out + ((size_t)b * S_LEN + row0B) * 128;
#pragma unroll
    for (int vb = 0; vb < 8; ++vb)
#pragma unroll
        for (int r = 0; r < 4; ++r) {
            unsafeAtomicAdd(&obA[(size_t)r * 128 + vb * 16 + n16], OA[vb][r]);
            unsafeAtomicAdd(&obB[(size_t)r * 128 + vb * 16 + n16], OB[vb][r]);
        }

    // -------- split-K fixup: last-arriving chunk normalizes this row-group ----
    __threadfence();                 // make this block's atomics agent-visible
    __syncthreads();                 // all threads fenced
    if (t == 0) {
        int old = atomicAdd(&cnt[b * 32 + qt], 1);
        sflag = (old == NCHUNK - 1);
    }
    __syncthreads();
    if (sflag) {
        __threadfence();             // acquire: see other chunks' atomics
        float* ob = out + ((size_t)b * S_LEN + qt * 128) * 128;
        const float* lb = lbuf + b * S_LEN + qt * 128;
        for (int i = t; i < 128 * 128; i += 256) {
            int row = i >> 7;
            float l = __hip_atomic_load(&lb[row], __ATOMIC_RELAXED, __HIP_MEMORY_SCOPE_AGENT);
            float v = __hip_atomic_load(&ob[i], __ATOMIC_RELAXED, __HIP_MEMORY_SCOPE_AGENT);
            ob[i] = v * (1.0f / l);
        }
    }
}

// ---------------- launch ------------------------------------------------------
extern "C" void kernel_launch(void* const* d_in, const int* in_sizes, int n_in,
                              void* d_out, int out_size, void* d_ws, size_t ws_size,
                              hipStream_t stream) {
    const float* x  = (const float*)d_in[0];
    const float* Wq = (const float*)d_in[1];
    const float* Wk = (const float*)d_in[2];
    const float* Wv = (const float*)d_in[3];
    float* out = (float*)d_out;

    _Float16* ws = (_Float16*)d_ws;
    int*      cnt  = (int*)d_ws;
    _Float16* Qh   = ws + WS_QH;
    _Float16* Kh   = ws + WS_KH;
    _Float16* Vt   = ws + WS_VT;
    float*    lbuf = (float*)(ws + WS_L);

    qkv_proj_kernel<<<NBATCH * S_LEN / 16, 256, 0, stream>>>(x, Wq, Wk, Wv, Qh, Kh, Vt,
                                                             (float4v*)out, (float4v*)lbuf, cnt);
    flash_kernel<<<dim3(S_LEN / 128, NCHUNK, NBATCH), 256, 0, stream>>>(Qh, Kh, Vt, out, lbuf, cnt);
}

// Round 6
// 151.428 us; speedup vs baseline: 1.9231x; 1.2118x over previous
//
#include <hip/hip_runtime.h>

typedef _Float16 half8 __attribute__((ext_vector_type(8)));
typedef _Float16 half4v __attribute__((ext_vector_type(4)));
typedef float   float4v __attribute__((ext_vector_type(4)));

#define S_LEN 4096
#define NBATCH 4
#define NCHUNK 8          // K-split factor: each chunk covers S/NCHUNK keys
// ws layout in halves:
//   W16  @ 0        : 256*128      = 32768
//   Qh   @ 32768    : 16384*64     = 1048576   (token-major [B*S][64])
//   Kh   @ 1081344  : 16384*64     = 1048576
//   Vt   @ 2129920  : 4*128*4096   = 2097152   (per-batch [128][S], PERMUTED per
//                     64-key tile: key k=grp*32+g*16+q*4+r stored at grp*32+q*8+g*4+r)
//   L    @ 4227072  : 16384 floats (row sum-of-exp accumulators)
#define WS_W16 0
#define WS_QH  32768
#define WS_KH  1081344
#define WS_VT  2129920
#define WS_L   4227072

// ---------------- kernel 0: zero accumulators + convert weights (fused) ------
__global__ __launch_bounds__(256) void init_kernel(const float* __restrict__ Wq,
                                                   const float* __restrict__ Wk,
                                                   const float* __restrict__ Wv,
                                                   _Float16* __restrict__ w16,
                                                   float4v* __restrict__ out4,
                                                   float4v* __restrict__ l4) {
    int i = blockIdx.x * 256 + threadIdx.x;   // 0..524287
    out4[i] = (float4v){0.f, 0.f, 0.f, 0.f};
    if (i < 4096) l4[i] = (float4v){0.f, 0.f, 0.f, 0.f};
    if (i < 32768) {
        int row = i >> 7, col = i & 127;
        float v;
        if (row < 64)       v = Wq[row * 128 + col];
        else if (row < 128) v = Wk[(row - 64) * 128 + col];
        else                v = Wv[(row - 128) * 128 + col];
        w16[i] = (_Float16)v;
    }
}

// ---------------- kernel 1: QKV projection via MFMA ---------------------------
// grid 1024 blocks x 256 thr; block owns 16 tokens; wave w owns oc [w*64, +64):
//   wave 0 -> Q, wave 1 -> K, waves 2,3 -> V.
__global__ __launch_bounds__(256) void qkv_proj_kernel(const float* __restrict__ x,
                                                       const _Float16* __restrict__ w16,
                                                       _Float16* __restrict__ Qh,
                                                       _Float16* __restrict__ Kh,
                                                       _Float16* __restrict__ Vt) {
    __shared__ _Float16 xs[16 * 136];   // 16 rows, stride 136 halves (pad 128->136)
    const int t = threadIdx.x;
    const int blk = blockIdx.x;
    const float* xb = x + (size_t)blk * 16 * 128;

    for (int it = 0; it < 2; ++it) {
        int i = t + it * 256;           // 0..511 float4
        int row = i >> 5, c4 = i & 31;
        float4v f = ((const float4v*)xb)[i];
        half4v h;
        h[0] = (_Float16)f[0]; h[1] = (_Float16)f[1];
        h[2] = (_Float16)f[2]; h[3] = (_Float16)f[3];
        *(half4v*)&xs[row * 136 + c4 * 4] = h;
    }
    __syncthreads();

    const int w = t >> 6, lane = t & 63, quad = lane >> 4, n16 = lane & 15;

    half8 a[4];
    for (int c = 0; c < 4; ++c)
        a[c] = *(const half8*)&xs[n16 * 136 + c * 32 + quad * 8];

    float4v acc[4];
    for (int nb = 0; nb < 4; ++nb) acc[nb] = (float4v){0.f, 0.f, 0.f, 0.f};

    for (int c = 0; c < 4; ++c) {
        for (int nb = 0; nb < 4; ++nb) {
            int oc = w * 64 + nb * 16 + n16;
            half8 bfr = *(const half8*)&w16[(size_t)oc * 128 + c * 32 + quad * 8];
            acc[nb] = __builtin_amdgcn_mfma_f32_16x16x32_f16(a[c], bfr, acc[nb], 0, 0, 0);
        }
    }

    const int token0 = blk * 16 + quad * 4;
    if (w == 0) {
        for (int nb = 0; nb < 4; ++nb)
            for (int r = 0; r < 4; ++r)
                Qh[(size_t)(token0 + r) * 64 + nb * 16 + n16] = (_Float16)acc[nb][r];
    } else if (w == 1) {
        for (int nb = 0; nb < 4; ++nb)
            for (int r = 0; r < 4; ++r)
                Kh[(size_t)(token0 + r) * 64 + nb * 16 + n16] = (_Float16)acc[nb][r];
    } else {
        // V store, PERMUTED within each 64-key tile so flash reads b128 frags:
        // key s = kt*64+grp*32+g*16+q*4+r  ->  pos = kt*64+grp*32+q*8+g*4+r
        // (validated in rounds 4-5). token0 % 4 == 0, so r spans a contiguous 4.
        const int bb = token0 >> 12, s0 = token0 & 4095;
        const int kt = s0 >> 6, k0 = s0 & 63;
        const int grp = k0 >> 5, k32 = k0 & 31;
        const int g = k32 >> 4, q = (k32 >> 2) & 3;
        const int off = kt * 64 + grp * 32 + q * 8 + g * 4;
        for (int nb = 0; nb < 4; ++nb) {
            const int vc = (w - 2) * 64 + nb * 16 + n16;
            half4v h;
            h[0] = (_Float16)acc[nb][0]; h[1] = (_Float16)acc[nb][1];
            h[2] = (_Float16)acc[nb][2]; h[3] = (_Float16)acc[nb][3];
            *(half4v*)&Vt[((size_t)bb * 128 + vc) * S_LEN + off] = h;
        }
    }
}

// ---------------- kernel 2: flash attention, K-split x8, 2 q-tiles/wave -------
// grid (S/128, NCHUNK, B), 256 threads. Wave w owns q rows:
//   set A: qt*128 + w*16 + [0,16)      set B: qt*128 + 64 + w*16 + [0,16)
// Round-3 proven schedule: barrier -> stage regs->LDS -> barrier -> issue
// next-tile loads -> QK^T -> softmax -> PV. NCHUNK=8 gives 1024 blocks =
// 4 blocks/CU = 4 waves/SIMD of TLP (round 3 had only 2).
// SWAPPED QK^T (mfma(K,Q)) keeps q lane-local -> P stays in registers; the
// permuted Vt layout makes PV's V fragments contiguous b128 in LDS.
// Shifted-exp softmax: p = exp(s*0.125 - 4) -- exactly additive across chunks;
// accumulate via HW fp32 atomics.
#define KT 64
__global__ __launch_bounds__(256) void flash_kernel(const _Float16* __restrict__ Qh,
                                                    const _Float16* __restrict__ Kh,
                                                    const _Float16* __restrict__ Vt,
                                                    float* __restrict__ out,
                                                    float* __restrict__ lbuf) {
    __shared__ _Float16 Ks[KT * 72];        // K tile [64][64], padded stride 72
    __shared__ _Float16 Vs[128 * 72];       // V^T tile [128][64] (permuted cols)

    const int t = threadIdx.x;
    const int qt = blockIdx.x, chunk = blockIdx.y, b = blockIdx.z;
    const int w = t >> 6, lane = t & 63, quad = lane >> 4, n16 = lane & 15;

    const size_t qrowA = (size_t)b * S_LEN + qt * 128 + w * 16 + n16;
    const size_t qrowB = qrowA + 64;
    half8 aQ0A = *(const half8*)&Qh[qrowA * 64 + quad * 8];
    half8 aQ1A = *(const half8*)&Qh[qrowA * 64 + 32 + quad * 8];
    half8 aQ0B = *(const half8*)&Qh[qrowB * 64 + quad * 8];
    half8 aQ1B = *(const half8*)&Qh[qrowB * 64 + 32 + quad * 8];

    float4v OA[8], OB[8];
#pragma unroll
    for (int vb = 0; vb < 8; ++vb) {
        OA[vb] = (float4v){0.f, 0.f, 0.f, 0.f};
        OB[vb] = (float4v){0.f, 0.f, 0.f, 0.f};
    }
    float lsumA = 0.f, lsumB = 0.f;

    const _Float16* Kb = Kh + (size_t)b * S_LEN * 64;
    const _Float16* Vb = Vt + (size_t)b * 128 * S_LEN;

    const int kt0 = chunk * (S_LEN / KT / NCHUNK);
    const int kt1 = kt0 + (S_LEN / KT / NCHUNK);

    const int kr0 = t >> 3, kc0 = t & 7;
    const int kr1 = (t + 256) >> 3;

    // -------- prologue: load tile kt0 into registers --------
    half8 kreg0, kreg1, vreg[4];
    {
        const half8* srcK = (const half8*)(Kb + (size_t)kt0 * KT * 64);
        kreg0 = srcK[t];
        kreg1 = srcK[t + 256];
#pragma unroll
        for (int it = 0; it < 4; ++it) {
            int i = t + it * 256, row = i >> 3, c8 = i & 7;
            vreg[it] = *(const half8*)&Vb[(size_t)row * S_LEN + kt0 * KT + c8 * 8];
        }
    }

    for (int kt = kt0; kt < kt1; ++kt) {
        __syncthreads();                          // all waves done reading prev tile
        *(half8*)&Ks[kr0 * 72 + kc0 * 8] = kreg0;
        *(half8*)&Ks[kr1 * 72 + kc0 * 8] = kreg1;
#pragma unroll
        for (int it = 0; it < 4; ++it) {
            int i = t + it * 256, row = i >> 3, c8 = i & 7;
            *(half8*)&Vs[row * 72 + c8 * 8] = vreg[it];
        }
        __syncthreads();                          // tile visible to all waves

        // issue next-tile loads; latency hides under the 48-MFMA compute body
        if (kt + 1 < kt1) {
            const half8* srcK = (const half8*)(Kb + (size_t)(kt + 1) * KT * 64);
            kreg0 = srcK[t];
            kreg1 = srcK[t + 256];
#pragma unroll
            for (int it = 0; it < 4; ++it) {
                int i = t + it * 256, row = i >> 3, c8 = i & 7;
                vreg[it] = *(const half8*)&Vb[(size_t)row * S_LEN + (kt + 1) * KT + c8 * 8];
            }
        }

        // -------- QK^T (swapped) + softmax; P packed into A-fragments --------
        half8 aP0A, aP1A, aP0B, aP1B;
        __builtin_amdgcn_s_setprio(1);
#pragma unroll
        for (int nb = 0; nb < 4; ++nb) {
            half8 bK0 = *(const half8*)&Ks[(nb * 16 + n16) * 72 + quad * 8];
            half8 bK1 = *(const half8*)&Ks[(nb * 16 + n16) * 72 + 32 + quad * 8];
            float4v scA = (float4v){0.f, 0.f, 0.f, 0.f};
            float4v scB = (float4v){0.f, 0.f, 0.f, 0.f};
            scA = __builtin_amdgcn_mfma_f32_16x16x32_f16(bK0, aQ0A, scA, 0, 0, 0);
            scA = __builtin_amdgcn_mfma_f32_16x16x32_f16(bK1, aQ1A, scA, 0, 0, 0);
            scB = __builtin_amdgcn_mfma_f32_16x16x32_f16(bK0, aQ0B, scB, 0, 0, 0);
            scB = __builtin_amdgcn_mfma_f32_16x16x32_f16(bK1, aQ1B, scB, 0, 0, 0);
#pragma unroll
            for (int r = 0; r < 4; ++r) {
                // exp(s*0.125 - 4) == exp2(fma(s, 0.125*log2e, -4*log2e))
                float pa = __builtin_amdgcn_exp2f(__builtin_fmaf(scA[r], 0.18033688f, -5.7707802f));
                lsumA += pa;
                float pb = __builtin_amdgcn_exp2f(__builtin_fmaf(scB[r], 0.18033688f, -5.7707802f));
                lsumB += pb;
                int slot = (nb & 1) * 4 + r;
                if (nb < 2) { aP0A[slot] = (_Float16)pa; aP0B[slot] = (_Float16)pb; }
                else        { aP1A[slot] = (_Float16)pa; aP1B[slot] = (_Float16)pb; }
            }
        }
        __builtin_amdgcn_s_setprio(0);

        // -------- PV: V frags contiguous b128 thanks to permuted layout -------
        __builtin_amdgcn_s_setprio(1);
#pragma unroll
        for (int vb = 0; vb < 8; ++vb) {
            const _Float16* vrow = &Vs[(vb * 16 + n16) * 72];
            half8 bV0 = *(const half8*)&vrow[quad * 8];
            half8 bV1 = *(const half8*)&vrow[32 + quad * 8];
            OA[vb] = __builtin_amdgcn_mfma_f32_16x16x32_f16(aP0A, bV0, OA[vb], 0, 0, 0);
            OA[vb] = __builtin_amdgcn_mfma_f32_16x16x32_f16(aP1A, bV1, OA[vb], 0, 0, 0);
            OB[vb] = __builtin_amdgcn_mfma_f32_16x16x32_f16(aP0B, bV0, OB[vb], 0, 0, 0);
            OB[vb] = __builtin_amdgcn_mfma_f32_16x16x32_f16(aP1B, bV1, OB[vb], 0, 0, 0);
        }
        __builtin_amdgcn_s_setprio(0);
    }

    // each lane holds the partial row-sum for q = n16; reduce across quads
    lsumA += __shfl_xor(lsumA, 16);
    lsumA += __shfl_xor(lsumA, 32);
    lsumB += __shfl_xor(lsumB, 16);
    lsumB += __shfl_xor(lsumB, 32);

    const int rowbaseA = qt * 128 + w * 16;                 // within batch
    const int rowbaseB = rowbaseA + 64;
    if (quad == 0) {
        unsafeAtomicAdd(&lbuf[b * S_LEN + rowbaseA + n16], lsumA);
        unsafeAtomicAdd(&lbuf[b * S_LEN + rowbaseB + n16], lsumB);
    }

    const int row0A = rowbaseA + quad * 4;
    const int row0B = rowbaseB + quad * 4;
    float* obA = out + ((size_t)b * S_LEN + row0A) * 128;
    float* obB = out + ((size_t)b * S_LEN + row0B) * 128;
#pragma unroll
    for (int vb = 0; vb < 8; ++vb)
#pragma unroll
        for (int r = 0; r < 4; ++r) {
            unsafeAtomicAdd(&obA[(size_t)r * 128 + vb * 16 + n16], OA[vb][r]);
            unsafeAtomicAdd(&obB[(size_t)r * 128 + vb * 16 + n16], OB[vb][r]);
        }
}

// ---------------- kernel 3: normalize out by row sums -------------------------
__global__ __launch_bounds__(256) void norm_kernel(float4v* __restrict__ out4,
                                                   const float* __restrict__ lbuf) {
    int i = blockIdx.x * 256 + threadIdx.x;   // 0..524287 (32 float4 per row)
    float inv = 1.0f / lbuf[i >> 5];
    float4v v = out4[i];
    v[0] *= inv; v[1] *= inv; v[2] *= inv; v[3] *= inv;
    out4[i] = v;
}

// ---------------- launch ------------------------------------------------------
extern "C" void kernel_launch(void* const* d_in, const int* in_sizes, int n_in,
                              void* d_out, int out_size, void* d_ws, size_t ws_size,
                              hipStream_t stream) {
    const float* x  = (const float*)d_in[0];
    const float* Wq = (const float*)d_in[1];
    const float* Wk = (const float*)d_in[2];
    const float* Wv = (const float*)d_in[3];
    float* out = (float*)d_out;

    _Float16* ws = (_Float16*)d_ws;
    _Float16* w16 = ws + WS_W16;
    _Float16* Qh  = ws + WS_QH;
    _Float16* Kh  = ws + WS_KH;
    _Float16* Vt  = ws + WS_VT;
    float*    lbuf = (float*)(ws + WS_L);

    init_kernel<<<2048, 256, 0, stream>>>(Wq, Wk, Wv, w16, (float4v*)out, (float4v*)lbuf);
    qkv_proj_kernel<<<NBATCH * S_LEN / 16, 256, 0, stream>>>(x, w16, Qh, Kh, Vt);
    flash_kernel<<<dim3(S_LEN / 128, NCHUNK, NBATCH), 256, 0, stream>>>(Qh, Kh, Vt, out, lbuf);
    norm_kernel<<<2048, 256, 0, stream>>>((float4v*)out, lbuf);
}

// Round 7
// 116.287 us; speedup vs baseline: 2.5042x; 1.3022x over previous
//
#include <hip/hip_runtime.h>

typedef _Float16 half8 __attribute__((ext_vector_type(8)));
typedef _Float16 half4v __attribute__((ext_vector_type(4)));
typedef float   float4v __attribute__((ext_vector_type(4)));

#define S_LEN 4096
#define NBATCH 4
#define NCHUNK 4          // K-split factor: each chunk covers S/NCHUNK keys
// ws layout in halves:
//   W16  @ 0        : 256*128      = 32768
//   Qh   @ 32768    : 16384*64     = 1048576   (token-major [B*S][64])
//   Kh   @ 1081344  : 16384*64     = 1048576
//   Vt   @ 2129920  : 4*128*4096   = 2097152   (per-batch [128][S], PERMUTED per
//                     64-key tile: key k=grp*32+g*16+q*4+r stored at grp*32+q*8+g*4+r)
//   L    @ 4227072  : 16384 floats (row sum-of-exp accumulators, fallback path)
// staged-path extras (byte offsets from ws base):
//   OACC @ 8519680  : NCHUNK*4*4096*128 fp32 = 32 MB   (per-chunk partial O)
//   LACC @ 42074112 : NCHUNK*4*4096 fp32     = 256 KB  (per-chunk partial l)
#define WS_W16 0
#define WS_QH  32768
#define WS_KH  1081344
#define WS_VT  2129920
#define WS_L   4227072
#define OACC_BYTE_OFF 8519680ull
#define OACC_F4_PER_CHUNK (NBATCH * S_LEN * 128 / 4)            // 524288
#define LACC_BYTE_OFF (OACC_BYTE_OFF + (unsigned long long)NCHUNK * NBATCH * S_LEN * 128 * 4)
#define WS_NEED_BYTES (LACC_BYTE_OFF + (unsigned long long)NCHUNK * NBATCH * S_LEN * 4)

// ---------------- kernel 0a: convert weights fp32 -> fp16, packed [256][128] --
__global__ __launch_bounds__(256) void wcvt_kernel(const float* __restrict__ Wq,
                                                   const float* __restrict__ Wk,
                                                   const float* __restrict__ Wv,
                                                   _Float16* __restrict__ w16) {
    int i = blockIdx.x * 256 + threadIdx.x;   // 0..32767
    int row = i >> 7, col = i & 127;
    float v;
    if (row < 64)       v = Wq[row * 128 + col];
    else if (row < 128) v = Wk[(row - 64) * 128 + col];
    else                v = Wv[(row - 128) * 128 + col];
    w16[i] = (_Float16)v;
}

// ---------------- kernel 0b (FALLBACK only): zero out + lbuf ------------------
__global__ __launch_bounds__(256) void zero_kernel(float4v* __restrict__ out4,
                                                   float4v* __restrict__ l4) {
    int i = blockIdx.x * 256 + threadIdx.x;   // 0..524287
    out4[i] = (float4v){0.f, 0.f, 0.f, 0.f};
    if (i < 4096) l4[i] = (float4v){0.f, 0.f, 0.f, 0.f};
}

// ---------------- kernel 1: QKV projection via MFMA ---------------------------
// grid 1024 blocks x 256 thr; block owns 16 tokens; wave w owns oc [w*64, +64):
//   wave 0 -> Q, wave 1 -> K, waves 2,3 -> V.
__global__ __launch_bounds__(256) void qkv_proj_kernel(const float* __restrict__ x,
                                                       const _Float16* __restrict__ w16,
                                                       _Float16* __restrict__ Qh,
                                                       _Float16* __restrict__ Kh,
                                                       _Float16* __restrict__ Vt) {
    __shared__ _Float16 xs[16 * 136];   // 16 rows, stride 136 halves (pad 128->136)
    const int t = threadIdx.x;
    const int blk = blockIdx.x;
    const float* xb = x + (size_t)blk * 16 * 128;

    for (int it = 0; it < 2; ++it) {
        int i = t + it * 256;           // 0..511 float4
        int row = i >> 5, c4 = i & 31;
        float4v f = ((const float4v*)xb)[i];
        half4v h;
        h[0] = (_Float16)f[0]; h[1] = (_Float16)f[1];
        h[2] = (_Float16)f[2]; h[3] = (_Float16)f[3];
        *(half4v*)&xs[row * 136 + c4 * 4] = h;
    }
    __syncthreads();

    const int w = t >> 6, lane = t & 63, quad = lane >> 4, n16 = lane & 15;

    half8 a[4];
    for (int c = 0; c < 4; ++c)
        a[c] = *(const half8*)&xs[n16 * 136 + c * 32 + quad * 8];

    float4v acc[4];
    for (int nb = 0; nb < 4; ++nb) acc[nb] = (float4v){0.f, 0.f, 0.f, 0.f};

    for (int c = 0; c < 4; ++c) {
        for (int nb = 0; nb < 4; ++nb) {
            int oc = w * 64 + nb * 16 + n16;
            half8 bfr = *(const half8*)&w16[(size_t)oc * 128 + c * 32 + quad * 8];
            acc[nb] = __builtin_amdgcn_mfma_f32_16x16x32_f16(a[c], bfr, acc[nb], 0, 0, 0);
        }
    }

    const int token0 = blk * 16 + quad * 4;
    if (w == 0) {
        for (int nb = 0; nb < 4; ++nb)
            for (int r = 0; r < 4; ++r)
                Qh[(size_t)(token0 + r) * 64 + nb * 16 + n16] = (_Float16)acc[nb][r];
    } else if (w == 1) {
        for (int nb = 0; nb < 4; ++nb)
            for (int r = 0; r < 4; ++r)
                Kh[(size_t)(token0 + r) * 64 + nb * 16 + n16] = (_Float16)acc[nb][r];
    } else {
        // V store, PERMUTED within each 64-key tile so flash reads b128 frags:
        // key s = kt*64+grp*32+g*16+q*4+r  ->  pos = kt*64+grp*32+q*8+g*4+r
        const int bb = token0 >> 12, s0 = token0 & 4095;
        const int kt = s0 >> 6, k0 = s0 & 63;
        const int grp = k0 >> 5, k32 = k0 & 31;
        const int g = k32 >> 4, q = (k32 >> 2) & 3;
        const int off = kt * 64 + grp * 32 + q * 8 + g * 4;
        for (int nb = 0; nb < 4; ++nb) {
            const int vc = (w - 2) * 64 + nb * 16 + n16;
            half4v h;
            h[0] = (_Float16)acc[nb][0]; h[1] = (_Float16)acc[nb][1];
            h[2] = (_Float16)acc[nb][2]; h[3] = (_Float16)acc[nb][3];
            *(half4v*)&Vt[((size_t)bb * 128 + vc) * S_LEN + off] = h;
        }
    }
}

// ---------------- kernel 2: flash attention, K-split x4, 2 q-tiles/wave -------
// grid (S/128, NCHUNK, B), 256 threads. Round-3 proven schedule (barrier ->
// stage -> barrier -> prefetch -> QK^T -> softmax -> PV).
// STAGED=true : epilogue writes partial (O, l) to per-chunk slices with PLAIN
//   streaming stores (no atomic RMW at HBM) -- norm_sum reduces them.
// STAGED=false: round-3 atomic epilogue (fallback when ws is too small).
#define KT 64
template <bool STAGED>
__global__ __launch_bounds__(256) void flash_kernel(const _Float16* __restrict__ Qh,
                                                    const _Float16* __restrict__ Kh,
                                                    const _Float16* __restrict__ Vt,
                                                    float* __restrict__ outp,
                                                    float* __restrict__ lp) {
    __shared__ _Float16 Ks[KT * 72];        // K tile [64][64], padded stride 72
    __shared__ _Float16 Vs[128 * 72];       // V^T tile [128][64] (permuted cols)

    const int t = threadIdx.x;
    const int qt = blockIdx.x, chunk = blockIdx.y, b = blockIdx.z;
    const int w = t >> 6, lane = t & 63, quad = lane >> 4, n16 = lane & 15;

    const size_t qrowA = (size_t)b * S_LEN + qt * 128 + w * 16 + n16;
    const size_t qrowB = qrowA + 64;
    half8 aQ0A = *(const half8*)&Qh[qrowA * 64 + quad * 8];
    half8 aQ1A = *(const half8*)&Qh[qrowA * 64 + 32 + quad * 8];
    half8 aQ0B = *(const half8*)&Qh[qrowB * 64 + quad * 8];
    half8 aQ1B = *(const half8*)&Qh[qrowB * 64 + 32 + quad * 8];

    float4v OA[8], OB[8];
#pragma unroll
    for (int vb = 0; vb < 8; ++vb) {
        OA[vb] = (float4v){0.f, 0.f, 0.f, 0.f};
        OB[vb] = (float4v){0.f, 0.f, 0.f, 0.f};
    }
    float lsumA = 0.f, lsumB = 0.f;

    const _Float16* Kb = Kh + (size_t)b * S_LEN * 64;
    const _Float16* Vb = Vt + (size_t)b * 128 * S_LEN;

    const int kt0 = chunk * (S_LEN / KT / NCHUNK);
    const int kt1 = kt0 + (S_LEN / KT / NCHUNK);

    const int kr0 = t >> 3, kc0 = t & 7;
    const int kr1 = (t + 256) >> 3;

    // -------- prologue: load tile kt0 into registers --------
    half8 kreg0, kreg1, vreg[4];
    {
        const half8* srcK = (const half8*)(Kb + (size_t)kt0 * KT * 64);
        kreg0 = srcK[t];
        kreg1 = srcK[t + 256];
#pragma unroll
        for (int it = 0; it < 4; ++it) {
            int i = t + it * 256, row = i >> 3, c8 = i & 7;
            vreg[it] = *(const half8*)&Vb[(size_t)row * S_LEN + kt0 * KT + c8 * 8];
        }
    }

    for (int kt = kt0; kt < kt1; ++kt) {
        __syncthreads();                          // all waves done reading prev tile
        *(half8*)&Ks[kr0 * 72 + kc0 * 8] = kreg0;
        *(half8*)&Ks[kr1 * 72 + kc0 * 8] = kreg1;
#pragma unroll
        for (int it = 0; it < 4; ++it) {
            int i = t + it * 256, row = i >> 3, c8 = i & 7;
            *(half8*)&Vs[row * 72 + c8 * 8] = vreg[it];
        }
        __syncthreads();                          // tile visible to all waves

        // issue next-tile loads; latency hides under the 48-MFMA compute body
        if (kt + 1 < kt1) {
            const half8* srcK = (const half8*)(Kb + (size_t)(kt + 1) * KT * 64);
            kreg0 = srcK[t];
            kreg1 = srcK[t + 256];
#pragma unroll
            for (int it = 0; it < 4; ++it) {
                int i = t + it * 256, row = i >> 3, c8 = i & 7;
                vreg[it] = *(const half8*)&Vb[(size_t)row * S_LEN + (kt + 1) * KT + c8 * 8];
            }
        }

        // -------- QK^T (swapped) + softmax; P packed into A-fragments --------
        half8 aP0A, aP1A, aP0B, aP1B;
        __builtin_amdgcn_s_setprio(1);
#pragma unroll
        for (int nb = 0; nb < 4; ++nb) {
            half8 bK0 = *(const half8*)&Ks[(nb * 16 + n16) * 72 + quad * 8];
            half8 bK1 = *(const half8*)&Ks[(nb * 16 + n16) * 72 + 32 + quad * 8];
            float4v scA = (float4v){0.f, 0.f, 0.f, 0.f};
            float4v scB = (float4v){0.f, 0.f, 0.f, 0.f};
            scA = __builtin_amdgcn_mfma_f32_16x16x32_f16(bK0, aQ0A, scA, 0, 0, 0);
            scA = __builtin_amdgcn_mfma_f32_16x16x32_f16(bK1, aQ1A, scA, 0, 0, 0);
            scB = __builtin_amdgcn_mfma_f32_16x16x32_f16(bK0, aQ0B, scB, 0, 0, 0);
            scB = __builtin_amdgcn_mfma_f32_16x16x32_f16(bK1, aQ1B, scB, 0, 0, 0);
#pragma unroll
            for (int r = 0; r < 4; ++r) {
                // exp(s*0.125 - 4) == exp2(fma(s, 0.125*log2e, -4*log2e))
                float pa = __builtin_amdgcn_exp2f(__builtin_fmaf(scA[r], 0.18033688f, -5.7707802f));
                lsumA += pa;
                float pb = __builtin_amdgcn_exp2f(__builtin_fmaf(scB[r], 0.18033688f, -5.7707802f));
                lsumB += pb;
                int slot = (nb & 1) * 4 + r;
                if (nb < 2) { aP0A[slot] = (_Float16)pa; aP0B[slot] = (_Float16)pb; }
                else        { aP1A[slot] = (_Float16)pa; aP1B[slot] = (_Float16)pb; }
            }
        }
        __builtin_amdgcn_s_setprio(0);

        // -------- PV: V frags contiguous b128 thanks to permuted layout -------
        __builtin_amdgcn_s_setprio(1);
#pragma unroll
        for (int vb = 0; vb < 8; ++vb) {
            const _Float16* vrow = &Vs[(vb * 16 + n16) * 72];
            half8 bV0 = *(const half8*)&vrow[quad * 8];
            half8 bV1 = *(const half8*)&vrow[32 + quad * 8];
            OA[vb] = __builtin_amdgcn_mfma_f32_16x16x32_f16(aP0A, bV0, OA[vb], 0, 0, 0);
            OA[vb] = __builtin_amdgcn_mfma_f32_16x16x32_f16(aP1A, bV1, OA[vb], 0, 0, 0);
            OB[vb] = __builtin_amdgcn_mfma_f32_16x16x32_f16(aP0B, bV0, OB[vb], 0, 0, 0);
            OB[vb] = __builtin_amdgcn_mfma_f32_16x16x32_f16(aP1B, bV1, OB[vb], 0, 0, 0);
        }
        __builtin_amdgcn_s_setprio(0);
    }

    // each lane holds the partial row-sum for q = n16; reduce across quads
    lsumA += __shfl_xor(lsumA, 16);
    lsumA += __shfl_xor(lsumA, 32);
    lsumB += __shfl_xor(lsumB, 16);
    lsumB += __shfl_xor(lsumB, 32);

    const int rowbaseA = qt * 128 + w * 16;                 // within batch
    const int rowbaseB = rowbaseA + 64;
    const int row0A = rowbaseA + quad * 4;
    const int row0B = rowbaseB + quad * 4;

    if (STAGED) {
        // plain streaming stores into this chunk's private slice
        const size_t cb = (size_t)chunk * NBATCH + b;
        if (quad == 0) {
            lp[cb * S_LEN + rowbaseA + n16] = lsumA;
            lp[cb * S_LEN + rowbaseB + n16] = lsumB;
        }
        float* obA = outp + (cb * S_LEN + row0A) * 128;
        float* obB = outp + (cb * S_LEN + row0B) * 128;
#pragma unroll
        for (int vb = 0; vb < 8; ++vb)
#pragma unroll
            for (int r = 0; r < 4; ++r) {
                obA[(size_t)r * 128 + vb * 16 + n16] = OA[vb][r];
                obB[(size_t)r * 128 + vb * 16 + n16] = OB[vb][r];
            }
    } else {
        if (quad == 0) {
            unsafeAtomicAdd(&lp[b * S_LEN + rowbaseA + n16], lsumA);
            unsafeAtomicAdd(&lp[b * S_LEN + rowbaseB + n16], lsumB);
        }
        float* obA = outp + ((size_t)b * S_LEN + row0A) * 128;
        float* obB = outp + ((size_t)b * S_LEN + row0B) * 128;
#pragma unroll
        for (int vb = 0; vb < 8; ++vb)
#pragma unroll
            for (int r = 0; r < 4; ++r) {
                unsafeAtomicAdd(&obA[(size_t)r * 128 + vb * 16 + n16], OA[vb][r]);
                unsafeAtomicAdd(&obB[(size_t)r * 128 + vb * 16 + n16], OB[vb][r]);
            }
    }
}

// ---------------- kernel 3a (STAGED): reduce chunk partials + normalize -------
__global__ __launch_bounds__(256) void norm_sum_kernel(const float4v* __restrict__ oacc4,
                                                       const float* __restrict__ lacc,
                                                       float4v* __restrict__ out4) {
    int i = blockIdx.x * 256 + threadIdx.x;   // 0..524287 (32 float4 per row)
    int row = i >> 5;                         // global row: b*4096 + r
    float l = 0.f;
#pragma unroll
    for (int c = 0; c < NCHUNK; ++c) l += lacc[c * (NBATCH * S_LEN) + row];
    float4v s = (float4v){0.f, 0.f, 0.f, 0.f};
#pragma unroll
    for (int c = 0; c < NCHUNK; ++c) {
        float4v p = oacc4[(size_t)c * OACC_F4_PER_CHUNK + i];
        s[0] += p[0]; s[1] += p[1]; s[2] += p[2]; s[3] += p[3];
    }
    float inv = 1.0f / l;
    s[0] *= inv; s[1] *= inv; s[2] *= inv; s[3] *= inv;
    out4[i] = s;
}

// ---------------- kernel 3b (FALLBACK): normalize out in place ----------------
__global__ __launch_bounds__(256) void norm_kernel(float4v* __restrict__ out4,
                                                   const float* __restrict__ lbuf) {
    int i = blockIdx.x * 256 + threadIdx.x;   // 0..524287
    float inv = 1.0f / lbuf[i >> 5];
    float4v v = out4[i];
    v[0] *= inv; v[1] *= inv; v[2] *= inv; v[3] *= inv;
    out4[i] = v;
}

// ---------------- launch ------------------------------------------------------
extern "C" void kernel_launch(void* const* d_in, const int* in_sizes, int n_in,
                              void* d_out, int out_size, void* d_ws, size_t ws_size,
                              hipStream_t stream) {
    const float* x  = (const float*)d_in[0];
    const float* Wq = (const float*)d_in[1];
    const float* Wk = (const float*)d_in[2];
    const float* Wv = (const float*)d_in[3];
    float* out = (float*)d_out;

    _Float16* ws = (_Float16*)d_ws;
    _Float16* w16 = ws + WS_W16;
    _Float16* Qh  = ws + WS_QH;
    _Float16* Kh  = ws + WS_KH;
    _Float16* Vt  = ws + WS_VT;
    float*    lbuf = (float*)(ws + WS_L);

    wcvt_kernel<<<128, 256, 0, stream>>>(Wq, Wk, Wv, w16);
    qkv_proj_kernel<<<NBATCH * S_LEN / 16, 256, 0, stream>>>(x, w16, Qh, Kh, Vt);

    if (ws_size >= (size_t)WS_NEED_BYTES) {
        float* oacc = (float*)((char*)d_ws + OACC_BYTE_OFF);
        float* lacc = (float*)((char*)d_ws + LACC_BYTE_OFF);
        flash_kernel<true><<<dim3(S_LEN / 128, NCHUNK, NBATCH), 256, 0, stream>>>(
            Qh, Kh, Vt, oacc, lacc);
        norm_sum_kernel<<<2048, 256, 0, stream>>>((const float4v*)oacc, lacc, (float4v*)out);
    } else {
        zero_kernel<<<2048, 256, 0, stream>>>((float4v*)out, (float4v*)lbuf);
        flash_kernel<false><<<dim3(S_LEN / 128, NCHUNK, NBATCH), 256, 0, stream>>>(
            Qh, Kh, Vt, out, lbuf);
        norm_kernel<<<2048, 256, 0, stream>>>((float4v*)out, lbuf);
    }
}